// Round 6
// baseline (423.888 us; speedup 1.0000x reference)
//
#include <hip/hip_runtime.h>
#include <math.h>

static constexpr int B  = 16384;
static constexpr int F  = 256;
static constexpr int NQ = 2048;
static constexpr int TS = 16;
static constexpr int KTOP = 8;
static constexpr int SPD = 272;   // 256 + 16
static constexpr int SPH = 68;
static constexpr int CD  = 278;   // 256+1+3+16+2
static constexpr int CH  = 69;

typedef __attribute__((ext_vector_type(8))) short bf16x8;
typedef __attribute__((ext_vector_type(4))) float f32x4;

__device__ inline short f2bf(float f) {
    unsigned u = __builtin_bit_cast(unsigned, f);
    unsigned r = (u + 0x7FFF + ((u >> 16) & 1)) >> 16;   // RNE
    return (short)r;
}

__device__ inline float fast_tanh(float o) {
    o = fminf(fmaxf(o, -15.0f), 15.0f);
    float e = __expf(2.0f * o);
    return (e - 1.0f) / (e + 1.0f);
}

// ---------------------------------------------------------------------------
// k_prepall (unchanged from R5): bf16 W^T buffers (padded) + qs transpose
// ---------------------------------------------------------------------------
__device__ inline void prep_one(const float* W, short* T, int local,
                                int K, int N, int KP) {
    const int n = local / KP, k = local - n * KP;
    T[local] = (k < K && n < N) ? f2bf(W[k * N + n]) : (short)0;
}

__global__ __launch_bounds__(256) void k_prepall(
    const float* __restrict__ gate_w1, const float* __restrict__ gate_w2,
    const float* __restrict__ bb_w,    const float* __restrict__ safe_w1,
    const float* __restrict__ spec_w1, const float* __restrict__ conf_w1,
    const float* __restrict__ qs,
    short* __restrict__ w1t, short* __restrict__ w2t, short* __restrict__ bbt,
    short* __restrict__ sw1t, short* __restrict__ spw1t, short* __restrict__ cfw1t,
    float* __restrict__ qs_t)
{
    const int idx = blockIdx.x * 256 + threadIdx.x;
    if (idx < 32768)       prep_one(gate_w1, w1t,  idx,           256, 128, 256);
    else if (idx < 65536)  prep_one(gate_w2, w2t,  idx - 32768,   128, 256, 128);
    else if (idx < 131072) prep_one(bb_w,    bbt,  idx - 65536,   256, 256, 256);
    else if (idx < 163840) prep_one(safe_w1, sw1t, idx - 131072,  256, 128, 256);
    else if (idx < 200704) prep_one(spec_w1, spw1t, idx - 163840, 272, 68, 288);
    else if (idx < 237568) prep_one(conf_w1, cfw1t, idx - 200704, 278, 69, 288);
    else if (idx < 761856) {
        const int local = idx - 237568;
        const int f = local >> 11, q = local & 2047;
        qs_t[local] = qs[q * 256 + f];
    }
}

// ---------------------------------------------------------------------------
// k_calib4: 4 rows/block. 3-level searchsorted with PARALLEL probe rounds:
//  L1: 15 LDS compares (16-way) -> 128-window
//  L2: 15 independent global loads (stride 8) -> 8-aligned 8-window
//  L3: two aligned float4 loads, count < x -> exact rank
// Then 4-row-batched stem MLP.
// ---------------------------------------------------------------------------
__global__ __launch_bounds__(256) void k_calib4(
    const float* __restrict__ x_num, const float* __restrict__ center,
    const float* __restrict__ scale, const float* __restrict__ qs,
    const float* __restrict__ qs_t,
    const float* __restrict__ sw1, const float* __restrict__ sb1,
    const float* __restrict__ sw2, const float* __restrict__ sb2,
    const float* __restrict__ sw3, const float* __restrict__ sb3,
    float* __restrict__ x_cal)
{
    __shared__ float cq[15][256];
    __shared__ float s_w1[48], s_b1[16], s_w2[256], s_b2[16], s_w3[16];
    const int tid = threadIdx.x;
    if (tid < 48) s_w1[tid] = sw1[tid];
    if (tid < 16) { s_b1[tid] = sb1[tid]; s_b2[tid] = sb2[tid]; s_w3[tid] = sw3[tid]; }
    s_w2[tid] = sw2[tid];
#pragma unroll
    for (int k = 0; k < 15; ++k) cq[k][tid] = qs[(k + 1) * 128 * 256 + tid];
    __syncthreads();

    const long b0 = (long)blockIdx.x * 4;
    const int f = tid;
    const float c = center[f];
    const float inv_sc = 1.0f / scale[f];

    float x[4], xr[4];
#pragma unroll
    for (int i = 0; i < 4; ++i) {
        x[i] = x_num[(b0 + i) * F + f];
        xr[i] = (x[i] - c) * inv_sc;
    }

    // L1: coarse (LDS)
    int cnt[4] = {0, 0, 0, 0};
#pragma unroll
    for (int k = 0; k < 15; ++k) {
        const float qv = cq[k][f];
#pragma unroll
        for (int i = 0; i < 4; ++i) cnt[i] += (qv < x[i]) ? 1 : 0;
    }
    const float* colp = qs_t + (long)f * NQ;

    // L2: 15 parallel probes per row at stride 8 inside the 128-window
    int lo2[4];
#pragma unroll
    for (int i = 0; i < 4; ++i) {
        const int lo = cnt[i] * 128;
        float qv[15];
#pragma unroll
        for (int j = 0; j < 15; ++j) qv[j] = colp[lo + 8 * (j + 1)];
        int c2 = 0;
#pragma unroll
        for (int j = 0; j < 15; ++j) c2 += (qv[j] < x[i]) ? 1 : 0;
        lo2[i] = lo + c2 * 8;
    }

    // L3: two aligned float4 loads cover the 8-window; count < x
    float xq[4];
#pragma unroll
    for (int i = 0; i < 4; ++i) {
        const float4 a = *reinterpret_cast<const float4*>(&colp[lo2[i]]);
        const float4 b = *reinterpret_cast<const float4*>(&colp[lo2[i] + 4]);
        int c3 = 0;
        c3 += (a.x < x[i]) ? 1 : 0; c3 += (a.y < x[i]) ? 1 : 0;
        c3 += (a.z < x[i]) ? 1 : 0; c3 += (a.w < x[i]) ? 1 : 0;
        c3 += (b.x < x[i]) ? 1 : 0; c3 += (b.y < x[i]) ? 1 : 0;
        c3 += (b.z < x[i]) ? 1 : 0; c3 += (b.w < x[i]) ? 1 : 0;
        const int rank = lo2[i] + c3;
        xq[i] = fminf((float)rank * (1.0f / (float)(NQ - 1)), 1.0f);
    }

    // stem MLP (4 rows batched)
    float h2[4][16];
#pragma unroll
    for (int j = 0; j < 16; ++j) {
        const float bb = s_b2[j];
#pragma unroll
        for (int i = 0; i < 4; ++i) h2[i][j] = bb;
    }
#pragma unroll 4
    for (int i16 = 0; i16 < 16; ++i16) {
        const float w0 = s_w1[i16], w1v = s_w1[16 + i16], w2v = s_w1[32 + i16];
        const float bb = s_b1[i16];
        float h1v[4];
#pragma unroll
        for (int i = 0; i < 4; ++i)
            h1v[i] = fmaxf(bb + x[i] * w0 + xr[i] * w1v + xq[i] * w2v, 0.0f);
        float wv[16];
        const float4* wr = reinterpret_cast<const float4*>(&s_w2[i16 * 16]);
        *reinterpret_cast<float4*>(&wv[0])  = wr[0];
        *reinterpret_cast<float4*>(&wv[4])  = wr[1];
        *reinterpret_cast<float4*>(&wv[8])  = wr[2];
        *reinterpret_cast<float4*>(&wv[12]) = wr[3];
#pragma unroll
        for (int j = 0; j < 16; ++j) {
#pragma unroll
            for (int i = 0; i < 4; ++i) h2[i][j] += h1v[i] * wv[j];
        }
    }
    float w3v[16];
    {
        const float4* wr = reinterpret_cast<const float4*>(&s_w3[0]);
        *reinterpret_cast<float4*>(&w3v[0])  = wr[0];
        *reinterpret_cast<float4*>(&w3v[4])  = wr[1];
        *reinterpret_cast<float4*>(&w3v[8])  = wr[2];
        *reinterpret_cast<float4*>(&w3v[12]) = wr[3];
    }
    const float b3 = sb3[0];
    float o[4] = {b3, b3, b3, b3};
#pragma unroll
    for (int j = 0; j < 16; ++j) {
#pragma unroll
        for (int i = 0; i < 4; ++i) o[i] += fmaxf(h2[i][j], 0.0f) * w3v[j];
    }
#pragma unroll
    for (int i = 0; i < 4; ++i)
        x_cal[(b0 + i) * F + f] = x[i] + 0.1f * fast_tanh(o[i]);
}

// ---------------------------------------------------------------------------
// k_mfma (unchanged from R5)
// ---------------------------------------------------------------------------
template <int K, int N, int ACT, int AMODE>
__global__ __launch_bounds__(256) void k_mfma(
    const float* __restrict__ A, const float* __restrict__ mul,
    const short* __restrict__ Wt, const float* __restrict__ bias,
    float* __restrict__ out)
{
    const int tid = threadIdx.x;
    const int wave = tid >> 6;
    const int lane = tid & 63;
    const int sub = lane & 15, quad = lane >> 4;
    const int wm = wave & 1, wn = wave >> 1;
    const long mrow = (long)blockIdx.x * 32 + wm * 16 + sub;
    const int n_base = blockIdx.y * 128 + wn * 64;

    f32x4 acc0 = {0,0,0,0}, acc1 = {0,0,0,0}, acc2 = {0,0,0,0}, acc3 = {0,0,0,0};

#pragma unroll
    for (int k0 = 0; k0 < K; k0 += 32) {
        const float* ap = A + mrow * K + k0 + quad * 8;
        float av[8];
        *reinterpret_cast<float4*>(&av[0]) = *reinterpret_cast<const float4*>(ap);
        *reinterpret_cast<float4*>(&av[4]) = *reinterpret_cast<const float4*>(ap + 4);
        if (AMODE == 1) {
            const float* mp = mul + mrow * K + k0 + quad * 8;
            float mv[8];
            *reinterpret_cast<float4*>(&mv[0]) = *reinterpret_cast<const float4*>(mp);
            *reinterpret_cast<float4*>(&mv[4]) = *reinterpret_cast<const float4*>(mp + 4);
#pragma unroll
            for (int j = 0; j < 8; ++j) av[j] *= mv[j];
        }
        bf16x8 afrag;
#pragma unroll
        for (int j = 0; j < 8; ++j) afrag[j] = f2bf(av[j]);

        const short* bp = Wt + (long)(n_base + sub) * K + k0 + quad * 8;
        const bf16x8 b0 = *reinterpret_cast<const bf16x8*>(bp);
        const bf16x8 b1 = *reinterpret_cast<const bf16x8*>(bp + 16 * K);
        const bf16x8 b2 = *reinterpret_cast<const bf16x8*>(bp + 32 * K);
        const bf16x8 b3 = *reinterpret_cast<const bf16x8*>(bp + 48 * K);
        acc0 = __builtin_amdgcn_mfma_f32_16x16x32_bf16(afrag, b0, acc0, 0, 0, 0);
        acc1 = __builtin_amdgcn_mfma_f32_16x16x32_bf16(afrag, b1, acc1, 0, 0, 0);
        acc2 = __builtin_amdgcn_mfma_f32_16x16x32_bf16(afrag, b2, acc2, 0, 0, 0);
        acc3 = __builtin_amdgcn_mfma_f32_16x16x32_bf16(afrag, b3, acc3, 0, 0, 0);
    }

    const long row_out = (long)blockIdx.x * 32 + wm * 16 + quad * 4;
    const f32x4 accs[4] = {acc0, acc1, acc2, acc3};
#pragma unroll
    for (int t = 0; t < 4; ++t) {
        const int col = n_base + t * 16 + sub;
        const float bb = bias[col];
#pragma unroll
        for (int r = 0; r < 4; ++r) {
            float v = accs[t][r] + bb;
            if (ACT == 0) v = fmaxf(v, 0.0f);
            else          v = 1.0f / (1.0f + __expf(-v));
            out[(row_out + r) * N + col] = v;
        }
    }
}

// ---------------------------------------------------------------------------
// k_topk (unchanged)
// ---------------------------------------------------------------------------
__global__ __launch_bounds__(64) void k_topk(
    const float* __restrict__ g, const float* __restrict__ x_cal,
    const float* __restrict__ tw1, const float* __restrict__ tb1,
    const float* __restrict__ tw2, const float* __restrict__ tb2,
    float* __restrict__ z_top, float* __restrict__ stats)
{
    __shared__ float s_hm[16];
    const int b = blockIdx.x;
    const int lane = threadIdx.x;
    const long base = (long)b * F;

    float gv[4];
#pragma unroll
    for (int i = 0; i < 4; ++i) gv[i] = g[base + lane + 64 * i];

    float s = gv[0] + gv[1] + gv[2] + gv[3];
    float mx = fmaxf(fmaxf(gv[0], gv[1]), fmaxf(gv[2], gv[3]));
    for (int m = 32; m; m >>= 1) {
        s  += __shfl_xor(s, m);
        mx  = fmaxf(mx, __shfl_xor(mx, m));
    }
    const float mean = s * (1.0f / 256.0f);
    float vs = 0.0f;
#pragma unroll
    for (int i = 0; i < 4; ++i) { float d = gv[i] - mean; vs += d * d; }
    for (int m = 32; m; m >>= 1) vs += __shfl_xor(vs, m);
    const float stdv = sqrtf(vs * (1.0f / 256.0f));

    float cur[4]; int curi[4];
#pragma unroll
    for (int i = 0; i < 4; ++i) { cur[i] = gv[i]; curi[i] = lane + 64 * i; }
    float tv[KTOP]; int ti[KTOP]; float vsum = 0.0f;
    for (int r = 0; r < KTOP; ++r) {
        float bv = cur[0]; int bi = curi[0];
#pragma unroll
        for (int i = 1; i < 4; ++i)
            if (cur[i] > bv || (cur[i] == bv && curi[i] < bi)) { bv = cur[i]; bi = curi[i]; }
        for (int m = 32; m; m >>= 1) {
            float ov = __shfl_xor(bv, m);
            int   oi = __shfl_xor(bi, m);
            if (ov > bv || (ov == bv && oi < bi)) { bv = ov; bi = oi; }
        }
        tv[r] = bv; ti[r] = bi; vsum += bv;
#pragma unroll
        for (int i = 0; i < 4; ++i) if (curi[i] == bi) cur[i] = -INFINITY;
    }
    const float denom = 1.0f / (vsum + 1e-6f);

    if (lane < 16) {
        float hm = 0.0f;
        for (int k = 0; k < KTOP; ++k) {
            const float xk = x_cal[base + ti[k]];
            const float xw = xk * (tv[k] * denom);
            hm += fmaxf(xw * tw1[lane] + tb1[lane], 0.0f);
        }
        s_hm[lane] = hm * (1.0f / (float)KTOP);
    }
    __syncthreads();
    if (lane < 16) {
        float z = tb2[lane];
#pragma unroll
        for (int j = 0; j < 16; ++j) z += s_hm[j] * tw2[j * 16 + lane];
        z_top[(long)b * TS + lane] = z;
    }
    if (lane == 0) {
        stats[(long)b * 4 + 0] = mean;
        stats[(long)b * 4 + 1] = mx;
        stats[(long)b * 4 + 2] = stdv;
    }
}

// ---------------------------------------------------------------------------
// k_tail3: fused heads, ROWS=16 (halved LDS -> ~29KB, grid 1024).
// 4 waves each own 32 output cols of the single 16-row m-tile.
// ---------------------------------------------------------------------------
static constexpr int HST = 260;   // s_h fp32 stride
static constexpr int AST = 312;   // s_a bf16 stride

template<int KP>
__device__ __forceinline__ void head_mfma16(
    const short* sa, const short* __restrict__ Wt,
    const float* __restrict__ b1v, const float* __restrict__ w2v, int Nreal,
    float (*s_red)[16], int wave, int sub, int quad)
{
    f32x4 acc[2];
#pragma unroll
    for (int t = 0; t < 2; ++t) acc[t] = (f32x4){0, 0, 0, 0};
#pragma unroll
    for (int k0 = 0; k0 < KP; k0 += 32) {
        const bf16x8 af = *reinterpret_cast<const bf16x8*>(
            &sa[sub * AST + k0 + quad * 8]);
#pragma unroll
        for (int t = 0; t < 2; ++t) {
            const int col = wave * 32 + t * 16 + sub;
            const bf16x8 bf = *reinterpret_cast<const bf16x8*>(
                &Wt[(long)col * KP + k0 + quad * 8]);
            acc[t] = __builtin_amdgcn_mfma_f32_16x16x32_bf16(af, bf, acc[t], 0, 0, 0);
        }
    }
    float rsum[4] = {0, 0, 0, 0};
#pragma unroll
    for (int t = 0; t < 2; ++t) {
        const int col = wave * 32 + t * 16 + sub;
        const float bb = (col < Nreal) ? b1v[col] : 0.0f;
        const float ww = (col < Nreal) ? w2v[col] : 0.0f;
#pragma unroll
        for (int rr = 0; rr < 4; ++rr)
            rsum[rr] += fmaxf(acc[t][rr] + bb, 0.0f) * ww;
    }
#pragma unroll
    for (int rr = 0; rr < 4; ++rr)
        for (int m = 1; m < 16; m <<= 1) rsum[rr] += __shfl_xor(rsum[rr], m);
    if (sub == 0) {
#pragma unroll
        for (int rr = 0; rr < 4; ++rr)
            s_red[wave][quad * 4 + rr] = rsum[rr];
    }
}

__global__ __launch_bounds__(256) void k_tail3(
    const float* __restrict__ h_base, const float* __restrict__ z_top,
    const float* __restrict__ gstats,
    const float* __restrict__ base_w, const float* __restrict__ base_b,
    const float* __restrict__ safe_lg, const float* __restrict__ safe_lb,
    const short* __restrict__ sw1t, const float* __restrict__ safe_b1,
    const float* __restrict__ safe_w2, const float* __restrict__ safe_b2,
    const float* __restrict__ spec_lg, const float* __restrict__ spec_lb,
    const short* __restrict__ spw1t, const float* __restrict__ spec_b1,
    const float* __restrict__ spec_w2, const float* __restrict__ spec_b2,
    const float* __restrict__ conf_lg, const float* __restrict__ conf_lb,
    const short* __restrict__ cfw1t, const float* __restrict__ conf_b1,
    const float* __restrict__ conf_w2, const float* __restrict__ conf_b2,
    float* __restrict__ out)
{
    __shared__ float s_h[16 * HST];
    __shared__ short s_a[16 * AST];
    __shared__ float s_z[16 * 16];
    __shared__ float s_g[16 * 4];
    __shared__ float s_sc[16 * 14];
    __shared__ float s_red[4][16];

    const int tid = threadIdx.x;
    const int wave = tid >> 6, lane = tid & 63;
    const int sub = lane & 15, quad = lane >> 4;
    const long row0 = (long)blockIdx.x * 16;

    // S0: stage inputs
    for (int idx = tid; idx < 16 * 64; idx += 256) {
        const int r = idx >> 6, q = idx & 63;
        *reinterpret_cast<float4*>(&s_h[r * HST + q * 4]) =
            *reinterpret_cast<const float4*>(&h_base[(row0 + r) * 256 + q * 4]);
    }
    if (tid < 256) { if (tid < 256) s_z[tid] = z_top[row0 * 16 + tid]; }
    if (tid < 64) s_g[tid] = gstats[row0 * 4 + tid];
    __syncthreads();

    // S1: per-row raw moments + y_base (16 lanes per row)
    {
        const int r = tid >> 4, l16 = tid & 15;
        float S = 0.0f, SS = 0.0f, Y = 0.0f;
#pragma unroll
        for (int i = 0; i < 16; ++i) {
            const int k = l16 + 16 * i;
            const float v = s_h[r * HST + k];
            S += v; SS += v * v; Y += v * base_w[k];
        }
        const float z0 = s_z[r * 16 + l16];
        float Sz = z0, SSz = z0 * z0;
#pragma unroll
        for (int m = 1; m < 16; m <<= 1) {
            S += __shfl_xor(S, m); SS += __shfl_xor(SS, m); Y += __shfl_xor(Y, m);
            Sz += __shfl_xor(Sz, m); SSz += __shfl_xor(SSz, m);
        }
        if (l16 == 0) {
            float* sc = &s_sc[r * 14];
            sc[0] = S; sc[1] = SS; sc[2] = Sz; sc[3] = SSz;
            sc[4] = Y + base_b[0];
            const float mu = S * (1.0f / 256.0f);
            sc[5] = mu;
            sc[6] = rsqrtf(SS * (1.0f / 256.0f) - mu * mu + 1e-5f);
            const float musp = (S + Sz) * (1.0f / (float)SPD);
            sc[7] = musp;
            sc[8] = rsqrtf((SS + SSz) * (1.0f / (float)SPD) - musp * musp + 1e-5f);
        }
    }
    __syncthreads();

    // S2a: safe LN -> bf16 A
    for (int idx = tid; idx < 16 * 128; idx += 256) {
        const int r = idx >> 7, k = (idx & 127) * 2;
        const float mu = s_sc[r * 14 + 5], rs = s_sc[r * 14 + 6];
        const float v0 = (s_h[r * HST + k] - mu) * rs * safe_lg[k] + safe_lb[k];
        const float v1 = (s_h[r * HST + k + 1] - mu) * rs * safe_lg[k + 1] + safe_lb[k + 1];
        const unsigned pk = (unsigned)(unsigned short)f2bf(v0) |
                            ((unsigned)(unsigned short)f2bf(v1) << 16);
        *reinterpret_cast<unsigned*>(&s_a[r * AST + k]) = pk;
    }
    __syncthreads();

    // S2b: safe MFMA
    head_mfma16<256>(s_a, sw1t, safe_b1, safe_w2, 128, s_red, wave, sub, quad);
    __syncthreads();

    // S2c: dsafe  +  S3a: spec LN -> bf16 A
    if (tid < 16)
        s_sc[tid * 14 + 9] = s_red[0][tid] + s_red[1][tid] + s_red[2][tid] + s_red[3][tid] + safe_b2[0];
    for (int idx = tid; idx < 16 * 144; idx += 256) {
        const int r = idx / 144, k = (idx - r * 144) * 2;
        const float mu = s_sc[r * 14 + 7], rs = s_sc[r * 14 + 8];
        float vv[2];
#pragma unroll
        for (int h = 0; h < 2; ++h) {
            const int kk = k + h;
            float raw = (kk < 256) ? s_h[r * HST + kk]
                       : (kk < SPD) ? s_z[r * 16 + kk - 256] : 0.0f;
            vv[h] = (kk < SPD) ? (raw - mu) * rs * spec_lg[kk] + spec_lb[kk] : 0.0f;
        }
        const unsigned pk = (unsigned)(unsigned short)f2bf(vv[0]) |
                            ((unsigned)(unsigned short)f2bf(vv[1]) << 16);
        *reinterpret_cast<unsigned*>(&s_a[r * AST + k]) = pk;
    }
    __syncthreads();

    // S3b: spec MFMA
    head_mfma16<288>(s_a, spw1t, spec_b1, spec_w2, SPH, s_red, wave, sub, quad);
    __syncthreads();

    // S3c: dspec + conf LN stats
    if (tid < 16) {
        float* sc = &s_sc[tid * 14];
        const float dsp = s_red[0][tid] + s_red[1][tid] + s_red[2][tid] + s_red[3][tid] + spec_b2[0];
        sc[10] = dsp;
        const float yb = sc[4];
        const float gm = s_g[tid * 4 + 0], gx = s_g[tid * 4 + 1], gs = s_g[tid * 4 + 2];
        const float ads = fabsf(sc[9]), adp = fabsf(dsp);
        const float es = yb + gm + gx + gs + ads + adp;
        const float eq = yb * yb + gm * gm + gx * gx + gs * gs + ads * ads + adp * adp;
        const float muc = (sc[0] + sc[2] + es) * (1.0f / (float)CD);
        sc[11] = muc;
        sc[12] = rsqrtf((sc[1] + sc[3] + eq) * (1.0f / (float)CD) - muc * muc + 1e-5f);
    }
    __syncthreads();

    // S4a: conf LN -> bf16 A
    for (int idx = tid; idx < 16 * 144; idx += 256) {
        const int r = idx / 144, k = (idx - r * 144) * 2;
        const float mu = s_sc[r * 14 + 11], rs = s_sc[r * 14 + 12];
        float vv[2];
#pragma unroll
        for (int h = 0; h < 2; ++h) {
            const int kk = k + h;
            float raw;
            if (kk < 256)       raw = s_h[r * HST + kk];
            else if (kk == 256) raw = s_sc[r * 14 + 4];
            else if (kk == 257) raw = s_g[r * 4 + 0];
            else if (kk == 258) raw = s_g[r * 4 + 1];
            else if (kk == 259) raw = s_g[r * 4 + 2];
            else if (kk < 276)  raw = s_z[r * 16 + kk - 260];
            else if (kk == 276) raw = fabsf(s_sc[r * 14 + 9]);
            else if (kk == 277) raw = fabsf(s_sc[r * 14 + 10]);
            else                raw = 0.0f;
            vv[h] = (kk < CD) ? (raw - mu) * rs * conf_lg[kk] + conf_lb[kk] : 0.0f;
        }
        const unsigned pk = (unsigned)(unsigned short)f2bf(vv[0]) |
                            ((unsigned)(unsigned short)f2bf(vv[1]) << 16);
        *reinterpret_cast<unsigned*>(&s_a[r * AST + k]) = pk;
    }
    __syncthreads();

    // S4b: conf MFMA
    head_mfma16<288>(s_a, cfw1t, conf_b1, conf_w2, CH, s_red, wave, sub, quad);
    __syncthreads();

    // S4c: gamma + output
    if (tid < 16) {
        const float* sc = &s_sc[tid * 14];
        const float gamma = 1.0f / (1.0f + __expf(
            -(s_red[0][tid] + s_red[1][tid] + s_red[2][tid] + s_red[3][tid] + conf_b2[0])));
        out[row0 + tid] = sc[4] + sc[9] + gamma * sc[10];
    }
}

// ---------------------------------------------------------------------------
extern "C" void kernel_launch(void* const* d_in, const int* in_sizes, int n_in,
                              void* d_out, int out_size, void* d_ws, size_t ws_size,
                              hipStream_t stream)
{
    const float* x_num   = (const float*)d_in[0];
    const float* center  = (const float*)d_in[1];
    const float* scale   = (const float*)d_in[2];
    const float* qs      = (const float*)d_in[3];
    const float* stem_w1 = (const float*)d_in[4];
    const float* stem_b1 = (const float*)d_in[5];
    const float* stem_w2 = (const float*)d_in[6];
    const float* stem_b2 = (const float*)d_in[7];
    const float* stem_w3 = (const float*)d_in[8];
    const float* stem_b3 = (const float*)d_in[9];
    const float* gate_w1 = (const float*)d_in[10];
    const float* gate_b1 = (const float*)d_in[11];
    const float* gate_w2 = (const float*)d_in[12];
    const float* gate_b2 = (const float*)d_in[13];
    const float* bb_w    = (const float*)d_in[14];
    const float* bb_b    = (const float*)d_in[15];
    const float* base_w  = (const float*)d_in[16];
    const float* base_b  = (const float*)d_in[17];
    const float* safe_lg = (const float*)d_in[18];
    const float* safe_lb = (const float*)d_in[19];
    const float* safe_w1 = (const float*)d_in[20];
    const float* safe_b1 = (const float*)d_in[21];
    const float* safe_w2 = (const float*)d_in[22];
    const float* safe_b2 = (const float*)d_in[23];
    const float* top_w1  = (const float*)d_in[24];
    const float* top_b1  = (const float*)d_in[25];
    const float* top_w2  = (const float*)d_in[26];
    const float* top_b2  = (const float*)d_in[27];
    const float* spec_lg = (const float*)d_in[28];
    const float* spec_lb = (const float*)d_in[29];
    const float* spec_w1 = (const float*)d_in[30];
    const float* spec_b1 = (const float*)d_in[31];
    const float* spec_w2 = (const float*)d_in[32];
    const float* spec_b2 = (const float*)d_in[33];
    const float* conf_lg = (const float*)d_in[34];
    const float* conf_lb = (const float*)d_in[35];
    const float* conf_w1 = (const float*)d_in[36];
    const float* conf_b1 = (const float*)d_in[37];
    const float* conf_w2 = (const float*)d_in[38];
    const float* conf_b2 = (const float*)d_in[39];

    float* ws    = (float*)d_ws;
    float* x_cal = ws;                         // B*256
    float* g_h   = x_cal + (long)B * 256;      // B*128
    float* g     = g_h   + (long)B * 128;      // B*256
    float* h_b   = g     + (long)B * 256;      // B*256  (qs_t aliases this region pre-backbone)
    float* z_top = h_b   + (long)B * 256;      // B*16
    float* gstat = z_top + (long)B * 16;       // B*4
    short* w1t   = (short*)(gstat + (long)B * 4);  // 128*256
    short* w2t   = w1t   + 128 * 256;              // 256*128
    short* bbt   = w2t   + 256 * 128;              // 256*256
    short* sw1t  = bbt   + 256 * 256;              // 128*256
    short* spw1t = sw1t  + 128 * 256;              // 128*288
    short* cfw1t = spw1t + 128 * 288;              // 128*288
    float* qs_t  = h_b;                            // 256*2048 floats, alias (dead after calib)
    float* out   = (float*)d_out;

    k_prepall<<<2976, 256, 0, stream>>>(gate_w1, gate_w2, bb_w, safe_w1, spec_w1,
                                        conf_w1, qs,
                                        w1t, w2t, bbt, sw1t, spw1t, cfw1t, qs_t);
    k_calib4<<<B / 4, 256, 0, stream>>>(x_num, center, scale, qs, qs_t,
                                        stem_w1, stem_b1, stem_w2, stem_b2, stem_w3, stem_b3,
                                        x_cal);
    k_mfma<256, 128, 0, 0><<<dim3(B / 32, 1), 256, 0, stream>>>(x_cal, nullptr, w1t, gate_b1, g_h);
    k_mfma<128, 256, 1, 0><<<dim3(B / 32, 2), 256, 0, stream>>>(g_h, nullptr, w2t, gate_b2, g);
    k_topk<<<B, 64, 0, stream>>>(g, x_cal, top_w1, top_b1, top_w2, top_b2, z_top, gstat);
    k_mfma<256, 256, 0, 1><<<dim3(B / 32, 2), 256, 0, stream>>>(x_cal, g, bbt, bb_b, h_b);
    k_tail3<<<B / 16, 256, 0, stream>>>(h_b, z_top, gstat,
                                        base_w, base_b,
                                        safe_lg, safe_lb, sw1t, safe_b1, safe_w2, safe_b2,
                                        spec_lg, spec_lb, spw1t, spec_b1, spec_w2, spec_b2,
                                        conf_lg, conf_lb, cfw1t, conf_b1, conf_w2, conf_b2,
                                        out);
}

// Round 7
// 311.944 us; speedup vs baseline: 1.3589x; 1.3589x over previous
//
#include <hip/hip_runtime.h>
#include <math.h>

static constexpr int B  = 16384;
static constexpr int F  = 256;
static constexpr int NQ = 2048;
static constexpr int TS = 16;
static constexpr int KTOP = 8;
static constexpr int SPD = 272;   // 256 + 16
static constexpr int SPH = 68;
static constexpr int CD  = 278;   // 256+1+3+16+2
static constexpr int CH  = 69;

typedef __attribute__((ext_vector_type(8))) short bf16x8;
typedef __attribute__((ext_vector_type(4))) float f32x4;

__device__ inline short f2bf(float f) {
    unsigned u = __builtin_bit_cast(unsigned, f);
    unsigned r = (u + 0x7FFF + ((u >> 16) & 1)) >> 16;   // RNE
    return (short)r;
}

__device__ inline float fast_tanh(float o) {
    o = fminf(fmaxf(o, -15.0f), 15.0f);
    float e = __expf(2.0f * o);
    return (e - 1.0f) / (e + 1.0f);
}

// ---------------------------------------------------------------------------
// k_prepall: bf16 W^T buffers (padded) + qs transpose (unchanged)
// ---------------------------------------------------------------------------
__device__ inline void prep_one(const float* W, short* T, int local,
                                int K, int N, int KP) {
    const int n = local / KP, k = local - n * KP;
    T[local] = (k < K && n < N) ? f2bf(W[k * N + n]) : (short)0;
}

__global__ __launch_bounds__(256) void k_prepall(
    const float* __restrict__ gate_w1, const float* __restrict__ gate_w2,
    const float* __restrict__ bb_w,    const float* __restrict__ safe_w1,
    const float* __restrict__ spec_w1, const float* __restrict__ conf_w1,
    const float* __restrict__ qs,
    short* __restrict__ w1t, short* __restrict__ w2t, short* __restrict__ bbt,
    short* __restrict__ sw1t, short* __restrict__ spw1t, short* __restrict__ cfw1t,
    float* __restrict__ qs_t)
{
    const int idx = blockIdx.x * 256 + threadIdx.x;
    if (idx < 32768)       prep_one(gate_w1, w1t,  idx,           256, 128, 256);
    else if (idx < 65536)  prep_one(gate_w2, w2t,  idx - 32768,   128, 256, 128);
    else if (idx < 131072) prep_one(bb_w,    bbt,  idx - 65536,   256, 256, 256);
    else if (idx < 163840) prep_one(safe_w1, sw1t, idx - 131072,  256, 128, 256);
    else if (idx < 200704) prep_one(spec_w1, spw1t, idx - 163840, 272, 68, 288);
    else if (idx < 237568) prep_one(conf_w1, cfw1t, idx - 200704, 278, 69, 288);
    else if (idx < 761856) {
        const int local = idx - 237568;
        const int f = local >> 11, q = local & 2047;
        qs_t[local] = qs[q * 256 + f];
    }
}

// ---------------------------------------------------------------------------
// k_calib5: thread = feature, 32 rows/block (grid 512).
// Exact searchsorted with ~1.5 L2 lines per search:
//   - 63-entry fp32 coarse table in LDS (boundaries qs[32(j+1)]): 6 LDS probes
//     -> 32-window (exact; bank = f&31 -> conflict-free)
//   - 1 global probe at window mid -> 16-half
//   - 4 float4 loads of ONE aligned 64B line, count(q < x) -> exact rank
// Then 8-row-interleaved stem MLP (weights via wave-uniform scalar loads).
// ---------------------------------------------------------------------------
__global__ __launch_bounds__(256) void k_calib5(
    const float* __restrict__ x_num, const float* __restrict__ center,
    const float* __restrict__ scale, const float* __restrict__ qs,
    const float* __restrict__ qs_t,
    const float* __restrict__ sw1, const float* __restrict__ sb1,
    const float* __restrict__ sw2, const float* __restrict__ sb2,
    const float* __restrict__ sw3, const float* __restrict__ sb3,
    float* __restrict__ x_cal)
{
    __shared__ float cq[63 * 256];          // 63 KB
    const int tid = threadIdx.x;
    const int f = tid;
#pragma unroll 1
    for (int j = 0; j < 63; ++j)
        cq[j * 256 + tid] = qs[(32 * (j + 1)) * 256 + tid];
    __syncthreads();

    const float c = center[f];
    const float inv_sc = 1.0f / scale[f];
    const float* colp = qs_t + (long)f * NQ;
    const long row_base = (long)blockIdx.x * 32;

#pragma unroll 1
    for (int grp = 0; grp < 4; ++grp) {
        const long r0 = row_base + grp * 8;
        float x[8], xr[8];
#pragma unroll
        for (int i = 0; i < 8; ++i) {
            x[i] = x_num[(r0 + i) * F + f];
            xr[i] = (x[i] - c) * inv_sc;
        }
        // coarse: 6-level binary search over 63 LDS boundaries
        int lo[8], hi[8];
#pragma unroll
        for (int i = 0; i < 8; ++i) { lo[i] = 0; hi[i] = 63; }
#pragma unroll
        for (int it = 0; it < 6; ++it) {
            float qv[8]; int mid[8];
#pragma unroll
            for (int i = 0; i < 8; ++i) {
                mid[i] = (lo[i] + hi[i]) >> 1;
                qv[i] = cq[mid[i] * 256 + f];
            }
#pragma unroll
            for (int i = 0; i < 8; ++i) {
                if (qv[i] < x[i]) lo[i] = mid[i] + 1; else hi[i] = mid[i];
            }
        }
        // probe mid of 32-window -> 16-half
        int base[8];
        {
            float pm[8];
#pragma unroll
            for (int i = 0; i < 8; ++i) pm[i] = colp[lo[i] * 32 + 16];
#pragma unroll
            for (int i = 0; i < 8; ++i)
                base[i] = lo[i] * 32 + ((pm[i] < x[i]) ? 16 : 0);
        }
        // one aligned 64B line: 4x float4, count < x
        float xq[8];
#pragma unroll
        for (int i = 0; i < 8; ++i) {
            const float4* wp = reinterpret_cast<const float4*>(&colp[base[i]]);
            const float4 a = wp[0], b = wp[1], d = wp[2], e = wp[3];
            int cN = 0;
            cN += (a.x < x[i]); cN += (a.y < x[i]); cN += (a.z < x[i]); cN += (a.w < x[i]);
            cN += (b.x < x[i]); cN += (b.y < x[i]); cN += (b.z < x[i]); cN += (b.w < x[i]);
            cN += (d.x < x[i]); cN += (d.y < x[i]); cN += (d.z < x[i]); cN += (d.w < x[i]);
            cN += (e.x < x[i]); cN += (e.y < x[i]); cN += (e.z < x[i]); cN += (e.w < x[i]);
            const int rank = base[i] + cN;
            xq[i] = fminf((float)rank * (1.0f / (float)(NQ - 1)), 1.0f);
        }
        // stem MLP: two sub-groups of 4 rows (register pressure)
#pragma unroll
        for (int hgrp = 0; hgrp < 2; ++hgrp) {
            const int o4 = hgrp * 4;
            float h2[4][16];
#pragma unroll
            for (int j = 0; j < 16; ++j) {
                const float bb = sb2[j];
#pragma unroll
                for (int i = 0; i < 4; ++i) h2[i][j] = bb;
            }
#pragma unroll 4
            for (int i16 = 0; i16 < 16; ++i16) {
                const float w0 = sw1[i16], w1v = sw1[16 + i16], w2v = sw1[32 + i16];
                const float bb = sb1[i16];
                float h1v[4];
#pragma unroll
                for (int i = 0; i < 4; ++i)
                    h1v[i] = fmaxf(bb + x[o4 + i] * w0 + xr[o4 + i] * w1v + xq[o4 + i] * w2v, 0.0f);
                float wv[16];
                const float4* wr = reinterpret_cast<const float4*>(&sw2[i16 * 16]);
                *reinterpret_cast<float4*>(&wv[0])  = wr[0];
                *reinterpret_cast<float4*>(&wv[4])  = wr[1];
                *reinterpret_cast<float4*>(&wv[8])  = wr[2];
                *reinterpret_cast<float4*>(&wv[12]) = wr[3];
#pragma unroll
                for (int j = 0; j < 16; ++j) {
#pragma unroll
                    for (int i = 0; i < 4; ++i) h2[i][j] += h1v[i] * wv[j];
                }
            }
            const float b3 = sb3[0];
            float o[4] = {b3, b3, b3, b3};
#pragma unroll
            for (int j = 0; j < 16; ++j) {
                const float w3v = sw3[j];
#pragma unroll
                for (int i = 0; i < 4; ++i) o[i] += fmaxf(h2[i][j], 0.0f) * w3v;
            }
#pragma unroll
            for (int i = 0; i < 4; ++i)
                x_cal[(r0 + o4 + i) * F + f] = x[o4 + i] + 0.1f * fast_tanh(o[i]);
        }
    }
}

// ---------------------------------------------------------------------------
// k_fused: gate1 (256->128 relu) -> gate2 (128->256 sigmoid, writes g) ->
//          backbone (x_cal*g, 256->256 relu, writes h_b). 32 rows/block.
// ---------------------------------------------------------------------------
static constexpr int ST1 = 136;   // bf16 stride for h1 (32x128)
static constexpr int ST2 = 264;   // bf16 stride for x_gated (32x256)

__global__ __launch_bounds__(256) void k_fused(
    const float* __restrict__ x_cal,
    const short* __restrict__ w1t, const float* __restrict__ gate_b1,
    const short* __restrict__ w2t, const float* __restrict__ gate_b2,
    const short* __restrict__ bbt, const float* __restrict__ bb_b,
    float* __restrict__ g, float* __restrict__ h_b)
{
    __shared__ short s_c1[32 * ST1];
    __shared__ short s_xg[32 * ST2];

    const int tid = threadIdx.x;
    const int wave = tid >> 6, lane = tid & 63;
    const int sub = lane & 15, quad = lane >> 4;
    const int wm = wave & 1, wn = wave >> 1;
    const long row0 = (long)blockIdx.x * 32;
    const long mrow = row0 + wm * 16 + sub;

    // ---- stage1: h1 = relu(x_cal @ W1 + b1), 32x128 ----
    {
        f32x4 acc[4];
#pragma unroll
        for (int t = 0; t < 4; ++t) acc[t] = (f32x4){0, 0, 0, 0};
#pragma unroll
        for (int k0 = 0; k0 < 256; k0 += 32) {
            const float* ap = x_cal + mrow * 256 + k0 + quad * 8;
            float av[8];
            *reinterpret_cast<float4*>(&av[0]) = *reinterpret_cast<const float4*>(ap);
            *reinterpret_cast<float4*>(&av[4]) = *reinterpret_cast<const float4*>(ap + 4);
            bf16x8 af;
#pragma unroll
            for (int j = 0; j < 8; ++j) af[j] = f2bf(av[j]);
#pragma unroll
            for (int t = 0; t < 4; ++t) {
                const int col = wn * 64 + t * 16 + sub;
                const bf16x8 bf = *reinterpret_cast<const bf16x8*>(
                    &w1t[(long)col * 256 + k0 + quad * 8]);
                acc[t] = __builtin_amdgcn_mfma_f32_16x16x32_bf16(af, bf, acc[t], 0, 0, 0);
            }
        }
#pragma unroll
        for (int t = 0; t < 4; ++t) {
            const int col = wn * 64 + t * 16 + sub;
            const float bb = gate_b1[col];
#pragma unroll
            for (int r = 0; r < 4; ++r) {
                const int rowl = wm * 16 + quad * 4 + r;
                s_c1[rowl * ST1 + col] = f2bf(fmaxf(acc[t][r] + bb, 0.0f));
            }
        }
    }
    __syncthreads();

    // ---- stage2: g = sigmoid(h1 @ W2 + b2), 32x256; build x_gated bf16 ----
    {
        f32x4 acc[8];
#pragma unroll
        for (int t = 0; t < 8; ++t) acc[t] = (f32x4){0, 0, 0, 0};
#pragma unroll
        for (int k0 = 0; k0 < 128; k0 += 32) {
            const bf16x8 af = *reinterpret_cast<const bf16x8*>(
                &s_c1[(wm * 16 + sub) * ST1 + k0 + quad * 8]);
#pragma unroll
            for (int t = 0; t < 8; ++t) {
                const int col = wn * 128 + t * 16 + sub;
                const bf16x8 bf = *reinterpret_cast<const bf16x8*>(
                    &w2t[(long)col * 128 + k0 + quad * 8]);
                acc[t] = __builtin_amdgcn_mfma_f32_16x16x32_bf16(af, bf, acc[t], 0, 0, 0);
            }
        }
#pragma unroll
        for (int t = 0; t < 8; ++t) {
            const int col = wn * 128 + t * 16 + sub;
            const float bb = gate_b2[col];
#pragma unroll
            for (int r = 0; r < 4; ++r) {
                const int rowl = wm * 16 + quad * 4 + r;
                const float gv = 1.0f / (1.0f + __expf(-(acc[t][r] + bb)));
                g[(row0 + rowl) * 256 + col] = gv;
                const float xg = x_cal[(row0 + rowl) * 256 + col] * gv;
                s_xg[rowl * ST2 + col] = f2bf(xg);
            }
        }
    }
    __syncthreads();

    // ---- stage3: h_b = relu(x_gated @ BB + bb_b), 32x256 ----
    {
        f32x4 acc[8];
#pragma unroll
        for (int t = 0; t < 8; ++t) acc[t] = (f32x4){0, 0, 0, 0};
#pragma unroll
        for (int k0 = 0; k0 < 256; k0 += 32) {
            const bf16x8 af = *reinterpret_cast<const bf16x8*>(
                &s_xg[(wm * 16 + sub) * ST2 + k0 + quad * 8]);
#pragma unroll
            for (int t = 0; t < 8; ++t) {
                const int col = wn * 128 + t * 16 + sub;
                const bf16x8 bf = *reinterpret_cast<const bf16x8*>(
                    &bbt[(long)col * 256 + k0 + quad * 8]);
                acc[t] = __builtin_amdgcn_mfma_f32_16x16x32_bf16(af, bf, acc[t], 0, 0, 0);
            }
        }
#pragma unroll
        for (int t = 0; t < 8; ++t) {
            const int col = wn * 128 + t * 16 + sub;
            const float bb = bb_b[col];
#pragma unroll
            for (int r = 0; r < 4; ++r) {
                const int rowl = wm * 16 + quad * 4 + r;
                h_b[(row0 + rowl) * 256 + col] = fmaxf(acc[t][r] + bb, 0.0f);
            }
        }
    }
}

// ---------------------------------------------------------------------------
// k_topk (unchanged)
// ---------------------------------------------------------------------------
__global__ __launch_bounds__(64) void k_topk(
    const float* __restrict__ g, const float* __restrict__ x_cal,
    const float* __restrict__ tw1, const float* __restrict__ tb1,
    const float* __restrict__ tw2, const float* __restrict__ tb2,
    float* __restrict__ z_top, float* __restrict__ stats)
{
    __shared__ float s_hm[16];
    const int b = blockIdx.x;
    const int lane = threadIdx.x;
    const long base = (long)b * F;

    float gv[4];
#pragma unroll
    for (int i = 0; i < 4; ++i) gv[i] = g[base + lane + 64 * i];

    float s = gv[0] + gv[1] + gv[2] + gv[3];
    float mx = fmaxf(fmaxf(gv[0], gv[1]), fmaxf(gv[2], gv[3]));
    for (int m = 32; m; m >>= 1) {
        s  += __shfl_xor(s, m);
        mx  = fmaxf(mx, __shfl_xor(mx, m));
    }
    const float mean = s * (1.0f / 256.0f);
    float vs = 0.0f;
#pragma unroll
    for (int i = 0; i < 4; ++i) { float d = gv[i] - mean; vs += d * d; }
    for (int m = 32; m; m >>= 1) vs += __shfl_xor(vs, m);
    const float stdv = sqrtf(vs * (1.0f / 256.0f));

    float cur[4]; int curi[4];
#pragma unroll
    for (int i = 0; i < 4; ++i) { cur[i] = gv[i]; curi[i] = lane + 64 * i; }
    float tv[KTOP]; int ti[KTOP]; float vsum = 0.0f;
    for (int r = 0; r < KTOP; ++r) {
        float bv = cur[0]; int bi = curi[0];
#pragma unroll
        for (int i = 1; i < 4; ++i)
            if (cur[i] > bv || (cur[i] == bv && curi[i] < bi)) { bv = cur[i]; bi = curi[i]; }
        for (int m = 32; m; m >>= 1) {
            float ov = __shfl_xor(bv, m);
            int   oi = __shfl_xor(bi, m);
            if (ov > bv || (ov == bv && oi < bi)) { bv = ov; bi = oi; }
        }
        tv[r] = bv; ti[r] = bi; vsum += bv;
#pragma unroll
        for (int i = 0; i < 4; ++i) if (curi[i] == bi) cur[i] = -INFINITY;
    }
    const float denom = 1.0f / (vsum + 1e-6f);

    if (lane < 16) {
        float hm = 0.0f;
        for (int k = 0; k < KTOP; ++k) {
            const float xk = x_cal[base + ti[k]];
            const float xw = xk * (tv[k] * denom);
            hm += fmaxf(xw * tw1[lane] + tb1[lane], 0.0f);
        }
        s_hm[lane] = hm * (1.0f / (float)KTOP);
    }
    __syncthreads();
    if (lane < 16) {
        float z = tb2[lane];
#pragma unroll
        for (int j = 0; j < 16; ++j) z += s_hm[j] * tw2[j * 16 + lane];
        z_top[(long)b * TS + lane] = z;
    }
    if (lane == 0) {
        stats[(long)b * 4 + 0] = mean;
        stats[(long)b * 4 + 1] = mx;
        stats[(long)b * 4 + 2] = stdv;
    }
}

// ---------------------------------------------------------------------------
// k_tail3 (unchanged from R6)
// ---------------------------------------------------------------------------
static constexpr int HST = 260;
static constexpr int AST = 312;

template<int KP>
__device__ __forceinline__ void head_mfma16(
    const short* sa, const short* __restrict__ Wt,
    const float* __restrict__ b1v, const float* __restrict__ w2v, int Nreal,
    float (*s_red)[16], int wave, int sub, int quad)
{
    f32x4 acc[2];
#pragma unroll
    for (int t = 0; t < 2; ++t) acc[t] = (f32x4){0, 0, 0, 0};
#pragma unroll
    for (int k0 = 0; k0 < KP; k0 += 32) {
        const bf16x8 af = *reinterpret_cast<const bf16x8*>(
            &sa[sub * AST + k0 + quad * 8]);
#pragma unroll
        for (int t = 0; t < 2; ++t) {
            const int col = wave * 32 + t * 16 + sub;
            const bf16x8 bf = *reinterpret_cast<const bf16x8*>(
                &Wt[(long)col * KP + k0 + quad * 8]);
            acc[t] = __builtin_amdgcn_mfma_f32_16x16x32_bf16(af, bf, acc[t], 0, 0, 0);
        }
    }
    float rsum[4] = {0, 0, 0, 0};
#pragma unroll
    for (int t = 0; t < 2; ++t) {
        const int col = wave * 32 + t * 16 + sub;
        const float bb = (col < Nreal) ? b1v[col] : 0.0f;
        const float ww = (col < Nreal) ? w2v[col] : 0.0f;
#pragma unroll
        for (int rr = 0; rr < 4; ++rr)
            rsum[rr] += fmaxf(acc[t][rr] + bb, 0.0f) * ww;
    }
#pragma unroll
    for (int rr = 0; rr < 4; ++rr)
        for (int m = 1; m < 16; m <<= 1) rsum[rr] += __shfl_xor(rsum[rr], m);
    if (sub == 0) {
#pragma unroll
        for (int rr = 0; rr < 4; ++rr)
            s_red[wave][quad * 4 + rr] = rsum[rr];
    }
}

__global__ __launch_bounds__(256) void k_tail3(
    const float* __restrict__ h_base, const float* __restrict__ z_top,
    const float* __restrict__ gstats,
    const float* __restrict__ base_w, const float* __restrict__ base_b,
    const float* __restrict__ safe_lg, const float* __restrict__ safe_lb,
    const short* __restrict__ sw1t, const float* __restrict__ safe_b1,
    const float* __restrict__ safe_w2, const float* __restrict__ safe_b2,
    const float* __restrict__ spec_lg, const float* __restrict__ spec_lb,
    const short* __restrict__ spw1t, const float* __restrict__ spec_b1,
    const float* __restrict__ spec_w2, const float* __restrict__ spec_b2,
    const float* __restrict__ conf_lg, const float* __restrict__ conf_lb,
    const short* __restrict__ cfw1t, const float* __restrict__ conf_b1,
    const float* __restrict__ conf_w2, const float* __restrict__ conf_b2,
    float* __restrict__ out)
{
    __shared__ float s_h[16 * HST];
    __shared__ short s_a[16 * AST];
    __shared__ float s_z[16 * 16];
    __shared__ float s_g[16 * 4];
    __shared__ float s_sc[16 * 14];
    __shared__ float s_red[4][16];

    const int tid = threadIdx.x;
    const int wave = tid >> 6, lane = tid & 63;
    const int sub = lane & 15, quad = lane >> 4;
    const long row0 = (long)blockIdx.x * 16;

    for (int idx = tid; idx < 16 * 64; idx += 256) {
        const int r = idx >> 6, q = idx & 63;
        *reinterpret_cast<float4*>(&s_h[r * HST + q * 4]) =
            *reinterpret_cast<const float4*>(&h_base[(row0 + r) * 256 + q * 4]);
    }
    if (tid < 256) s_z[tid] = z_top[row0 * 16 + tid];
    if (tid < 64) s_g[tid] = gstats[row0 * 4 + tid];
    __syncthreads();

    {
        const int r = tid >> 4, l16 = tid & 15;
        float S = 0.0f, SS = 0.0f, Y = 0.0f;
#pragma unroll
        for (int i = 0; i < 16; ++i) {
            const int k = l16 + 16 * i;
            const float v = s_h[r * HST + k];
            S += v; SS += v * v; Y += v * base_w[k];
        }
        const float z0 = s_z[r * 16 + l16];
        float Sz = z0, SSz = z0 * z0;
#pragma unroll
        for (int m = 1; m < 16; m <<= 1) {
            S += __shfl_xor(S, m); SS += __shfl_xor(SS, m); Y += __shfl_xor(Y, m);
            Sz += __shfl_xor(Sz, m); SSz += __shfl_xor(SSz, m);
        }
        if (l16 == 0) {
            float* sc = &s_sc[r * 14];
            sc[0] = S; sc[1] = SS; sc[2] = Sz; sc[3] = SSz;
            sc[4] = Y + base_b[0];
            const float mu = S * (1.0f / 256.0f);
            sc[5] = mu;
            sc[6] = rsqrtf(SS * (1.0f / 256.0f) - mu * mu + 1e-5f);
            const float musp = (S + Sz) * (1.0f / (float)SPD);
            sc[7] = musp;
            sc[8] = rsqrtf((SS + SSz) * (1.0f / (float)SPD) - musp * musp + 1e-5f);
        }
    }
    __syncthreads();

    for (int idx = tid; idx < 16 * 128; idx += 256) {
        const int r = idx >> 7, k = (idx & 127) * 2;
        const float mu = s_sc[r * 14 + 5], rs = s_sc[r * 14 + 6];
        const float v0 = (s_h[r * HST + k] - mu) * rs * safe_lg[k] + safe_lb[k];
        const float v1 = (s_h[r * HST + k + 1] - mu) * rs * safe_lg[k + 1] + safe_lb[k + 1];
        const unsigned pk = (unsigned)(unsigned short)f2bf(v0) |
                            ((unsigned)(unsigned short)f2bf(v1) << 16);
        *reinterpret_cast<unsigned*>(&s_a[r * AST + k]) = pk;
    }
    __syncthreads();

    head_mfma16<256>(s_a, sw1t, safe_b1, safe_w2, 128, s_red, wave, sub, quad);
    __syncthreads();

    if (tid < 16)
        s_sc[tid * 14 + 9] = s_red[0][tid] + s_red[1][tid] + s_red[2][tid] + s_red[3][tid] + safe_b2[0];
    for (int idx = tid; idx < 16 * 144; idx += 256) {
        const int r = idx / 144, k = (idx - r * 144) * 2;
        const float mu = s_sc[r * 14 + 7], rs = s_sc[r * 14 + 8];
        float vv[2];
#pragma unroll
        for (int h = 0; h < 2; ++h) {
            const int kk = k + h;
            float raw = (kk < 256) ? s_h[r * HST + kk]
                       : (kk < SPD) ? s_z[r * 16 + kk - 256] : 0.0f;
            vv[h] = (kk < SPD) ? (raw - mu) * rs * spec_lg[kk] + spec_lb[kk] : 0.0f;
        }
        const unsigned pk = (unsigned)(unsigned short)f2bf(vv[0]) |
                            ((unsigned)(unsigned short)f2bf(vv[1]) << 16);
        *reinterpret_cast<unsigned*>(&s_a[r * AST + k]) = pk;
    }
    __syncthreads();

    head_mfma16<288>(s_a, spw1t, spec_b1, spec_w2, SPH, s_red, wave, sub, quad);
    __syncthreads();

    if (tid < 16) {
        float* sc = &s_sc[tid * 14];
        const float dsp = s_red[0][tid] + s_red[1][tid] + s_red[2][tid] + s_red[3][tid] + spec_b2[0];
        sc[10] = dsp;
        const float yb = sc[4];
        const float gm = s_g[tid * 4 + 0], gx = s_g[tid * 4 + 1], gs = s_g[tid * 4 + 2];
        const float ads = fabsf(sc[9]), adp = fabsf(dsp);
        const float es = yb + gm + gx + gs + ads + adp;
        const float eq = yb * yb + gm * gm + gx * gx + gs * gs + ads * ads + adp * adp;
        const float muc = (sc[0] + sc[2] + es) * (1.0f / (float)CD);
        sc[11] = muc;
        sc[12] = rsqrtf((sc[1] + sc[3] + eq) * (1.0f / (float)CD) - muc * muc + 1e-5f);
    }
    __syncthreads();

    for (int idx = tid; idx < 16 * 144; idx += 256) {
        const int r = idx / 144, k = (idx - r * 144) * 2;
        const float mu = s_sc[r * 14 + 11], rs = s_sc[r * 14 + 12];
        float vv[2];
#pragma unroll
        for (int h = 0; h < 2; ++h) {
            const int kk = k + h;
            float raw;
            if (kk < 256)       raw = s_h[r * HST + kk];
            else if (kk == 256) raw = s_sc[r * 14 + 4];
            else if (kk == 257) raw = s_g[r * 4 + 0];
            else if (kk == 258) raw = s_g[r * 4 + 1];
            else if (kk == 259) raw = s_g[r * 4 + 2];
            else if (kk < 276)  raw = s_z[r * 16 + kk - 260];
            else if (kk == 276) raw = fabsf(s_sc[r * 14 + 9]);
            else if (kk == 277) raw = fabsf(s_sc[r * 14 + 10]);
            else                raw = 0.0f;
            vv[h] = (kk < CD) ? (raw - mu) * rs * conf_lg[kk] + conf_lb[kk] : 0.0f;
        }
        const unsigned pk = (unsigned)(unsigned short)f2bf(vv[0]) |
                            ((unsigned)(unsigned short)f2bf(vv[1]) << 16);
        *reinterpret_cast<unsigned*>(&s_a[r * AST + k]) = pk;
    }
    __syncthreads();

    head_mfma16<288>(s_a, cfw1t, conf_b1, conf_w2, CH, s_red, wave, sub, quad);
    __syncthreads();

    if (tid < 16) {
        const float* sc = &s_sc[tid * 14];
        const float gamma = 1.0f / (1.0f + __expf(
            -(s_red[0][tid] + s_red[1][tid] + s_red[2][tid] + s_red[3][tid] + conf_b2[0])));
        out[row0 + tid] = sc[4] + sc[9] + gamma * sc[10];
    }
}

// ---------------------------------------------------------------------------
extern "C" void kernel_launch(void* const* d_in, const int* in_sizes, int n_in,
                              void* d_out, int out_size, void* d_ws, size_t ws_size,
                              hipStream_t stream)
{
    const float* x_num   = (const float*)d_in[0];
    const float* center  = (const float*)d_in[1];
    const float* scale   = (const float*)d_in[2];
    const float* qs      = (const float*)d_in[3];
    const float* stem_w1 = (const float*)d_in[4];
    const float* stem_b1 = (const float*)d_in[5];
    const float* stem_w2 = (const float*)d_in[6];
    const float* stem_b2 = (const float*)d_in[7];
    const float* stem_w3 = (const float*)d_in[8];
    const float* stem_b3 = (const float*)d_in[9];
    const float* gate_w1 = (const float*)d_in[10];
    const float* gate_b1 = (const float*)d_in[11];
    const float* gate_w2 = (const float*)d_in[12];
    const float* gate_b2 = (const float*)d_in[13];
    const float* bb_w    = (const float*)d_in[14];
    const float* bb_b    = (const float*)d_in[15];
    const float* base_w  = (const float*)d_in[16];
    const float* base_b  = (const float*)d_in[17];
    const float* safe_lg = (const float*)d_in[18];
    const float* safe_lb = (const float*)d_in[19];
    const float* safe_w1 = (const float*)d_in[20];
    const float* safe_b1 = (const float*)d_in[21];
    const float* safe_w2 = (const float*)d_in[22];
    const float* safe_b2 = (const float*)d_in[23];
    const float* top_w1  = (const float*)d_in[24];
    const float* top_b1  = (const float*)d_in[25];
    const float* top_w2  = (const float*)d_in[26];
    const float* top_b2  = (const float*)d_in[27];
    const float* spec_lg = (const float*)d_in[28];
    const float* spec_lb = (const float*)d_in[29];
    const float* spec_w1 = (const float*)d_in[30];
    const float* spec_b1 = (const float*)d_in[31];
    const float* spec_w2 = (const float*)d_in[32];
    const float* spec_b2 = (const float*)d_in[33];
    const float* conf_lg = (const float*)d_in[34];
    const float* conf_lb = (const float*)d_in[35];
    const float* conf_w1 = (const float*)d_in[36];
    const float* conf_b1 = (const float*)d_in[37];
    const float* conf_w2 = (const float*)d_in[38];
    const float* conf_b2 = (const float*)d_in[39];

    float* ws    = (float*)d_ws;
    float* x_cal = ws;                         // B*256
    float* g_h   = x_cal + (long)B * 256;      // B*128 (unused, kept for layout)
    float* g     = g_h   + (long)B * 128;      // B*256
    float* h_b   = g     + (long)B * 256;      // B*256  (qs_t aliases; dead after calib)
    float* z_top = h_b   + (long)B * 256;      // B*16
    float* gstat = z_top + (long)B * 16;       // B*4
    short* w1t   = (short*)(gstat + (long)B * 4);  // 128*256
    short* w2t   = w1t   + 128 * 256;              // 256*128
    short* bbt   = w2t   + 256 * 128;              // 256*256
    short* sw1t  = bbt   + 256 * 256;              // 128*256
    short* spw1t = sw1t  + 128 * 256;              // 128*288
    short* cfw1t = spw1t + 128 * 288;              // 128*288
    float* qs_t  = h_b;                            // alias
    float* out   = (float*)d_out;

    k_prepall<<<2976, 256, 0, stream>>>(gate_w1, gate_w2, bb_w, safe_w1, spec_w1,
                                        conf_w1, qs,
                                        w1t, w2t, bbt, sw1t, spw1t, cfw1t, qs_t);
    k_calib5<<<512, 256, 0, stream>>>(x_num, center, scale, qs, qs_t,
                                      stem_w1, stem_b1, stem_w2, stem_b2, stem_w3, stem_b3,
                                      x_cal);
    k_fused<<<512, 256, 0, stream>>>(x_cal, w1t, gate_b1, w2t, gate_b2, bbt, bb_b,
                                     g, h_b);
    k_topk<<<B, 64, 0, stream>>>(g, x_cal, top_w1, top_b1, top_w2, top_b2, z_top, gstat);
    k_tail3<<<B / 16, 256, 0, stream>>>(h_b, z_top, gstat,
                                        base_w, base_b,
                                        safe_lg, safe_lb, sw1t, safe_b1, safe_w2, safe_b2,
                                        spec_lg, spec_lb, spw1t, spec_b1, spec_w2, spec_b2,
                                        conf_lg, conf_lb, cfw1t, conf_b1, conf_w2, conf_b2,
                                        out);
}